// Round 7
// baseline (233.761 us; speedup 1.0000x reference)
//
#include <hip/hip_runtime.h>
#include <hip/hip_bf16.h>
#include <cstdint>
#include <cstddef>

// Problem constants (fixed by reference)
#define BB 32
#define NN 8192
#define DIN 64
#define DOUT 128
#define NR 4
#define BN_EPS 1e-5f

typedef float nfloat4 __attribute__((ext_vector_type(4)));
typedef float floatx4 __attribute__((ext_vector_type(4)));
typedef short short8 __attribute__((ext_vector_type(8)));

// Workspace: [0, 64KB) uint smax_keys[B*NR*128]
// (memset 0 each launch; key 0 decodes below any real value's key)

__device__ inline void pack2(float a, float b, short8& dst, int idx) {
  // packed f32x2 -> bf16x2 (compiler emits v_cvt_pk_bf16_f32 on gfx950)
  __hip_bfloat162 h = __float22bfloat162_rn(make_float2(a, b));
  const unsigned int bits = *(unsigned int*)&h;
  dst[idx] = (short)(bits & 0xffffu);
  dst[idx + 1] = (short)(bits >> 16);
}

// LDS 16B-group swizzle: distinct across any 8 consecutive lanes for BOTH
// the stage writes (n = 4*lane+i) and the fragment reads (n = T*16+l16).
__device__ inline int swz(int n) { return (n ^ (n >> 2) ^ (n >> 5)) & 7; }

// ---------------------------------------------------------------------------
// K1 (MFMA): block = (b, 256-point chunk), 4 waves. Wave w owns channel
// tiles {w, w+4} (32 chans). r4 structure (passed @ ~75us): wave reads its
// 16 d-rows as 1KB sequential float4 bursts, in-register 8x4 transpose,
// bf16 pack, swizzled ds_write_b128; T-loop = 2 ds_read_b128 + 16 MFMA.
// CHANGE vs r4: the masked segment-max is now `if (rr==r) rmax=fmax(...)`
// -- exec-masked v_max (9 insts per (T,r)) instead of cndmask+fmax pairs
// (16 insts). MFMA stays OUTSIDE the divergent if (convergent, not sunk).
// r0 arithmetic: mask-max was ~half the ~1600 VALU/wave at 31% busy.
__global__ void __launch_bounds__(256) k_compute(
    const float* __restrict__ x, const float* __restrict__ W,
    const int* __restrict__ ring, unsigned int* __restrict__ smax_keys) {
  const int b = blockIdx.y;
  const int n0 = blockIdx.x * 256;
  const int wave = (int)threadIdx.x >> 6;
  const int lane = (int)threadIdx.x & 63;
  const int quad = lane >> 4;
  const int l16 = lane & 15;
  const float* xb = x + (size_t)b * DIN * NN;
  const int* rgb = ring + (size_t)b * NN;

  // bf16 tile, [n=256][8 groups of 8 d], 16B units, XOR-swizzled: 32 KB
  __shared__ short8 lx[256 * 8];

  // ---- stage: wave w reads rows d = w*16 .. w*16+15 (1KB sequential per
  // row per wave-instr), in-register transpose, bf16 pack, swizzled write.
  {
    const float* xr = xb + (size_t)(wave * 16) * NN + n0 + 4 * lane;
#pragma unroll
    for (int grp = 0; grp < 2; ++grp) {
      nfloat4 L[8];
#pragma unroll
      for (int j = 0; j < 8; ++j)
        L[j] = *(const nfloat4*)&xr[(size_t)(grp * 8 + j) * NN];
#pragma unroll
      for (int i = 0; i < 4; ++i) {
        short8 v;
        pack2(L[0][i], L[1][i], v, 0);
        pack2(L[2][i], L[3][i], v, 2);
        pack2(L[4][i], L[5][i], v, 4);
        pack2(L[6][i], L[7][i], v, 6);
        const int ni = 4 * lane + i;  // point column within the tile
        lx[ni * 8 + ((wave * 2 + grp) ^ swz(ni))] = v;
      }
    }
  }

  // A fragments for all 4 rings: afr[r][tile][kstep], A[m=l16][k=quad*8+j].
  short8 afr[NR][2][2];
#pragma unroll
  for (int r = 0; r < NR; ++r) {
#pragma unroll
    for (int tt = 0; tt < 2; ++tt) {
      const int chan = (wave + 4 * tt) * 16 + l16;
      const float* wr = W + ((size_t)r * DOUT + chan) * DIN + quad * 8;
#pragma unroll
      for (int ks = 0; ks < 2; ++ks) {
        const float4 w0 = *(const float4*)&wr[ks * 32];
        const float4 w1 = *(const float4*)&wr[ks * 32 + 4];
        short8 a;
        pack2(w0.x, w0.y, a, 0);
        pack2(w0.z, w0.w, a, 2);
        pack2(w1.x, w1.y, a, 4);
        pack2(w1.z, w1.w, a, 6);
        afr[r][tt][ks] = a;
      }
    }
  }

  floatx4 rmax[2][NR];
#pragma unroll
  for (int tt = 0; tt < 2; ++tt)
#pragma unroll
    for (int r = 0; r < NR; ++r)
      rmax[tt][r] = {-INFINITY, -INFINITY, -INFINITY, -INFINITY};

  __syncthreads();  // staged tile visible to all waves

#pragma unroll 4
  for (int T = 0; T < 16; ++T) {
    const int n = T * 16 + l16;
    const short8 b0 = lx[n * 8 + (quad ^ swz(n))];        // d = quad*8+j
    const short8 b1 = lx[n * 8 + ((4 + quad) ^ swz(n))];  // d = 32+quad*8+j
    const int rr = rgb[n0 + n];
#pragma unroll
    for (int r = 0; r < NR; ++r) {
      floatx4 acc0 = {0.f, 0.f, 0.f, 0.f};
      floatx4 acc1 = {0.f, 0.f, 0.f, 0.f};
      acc0 = __builtin_amdgcn_mfma_f32_16x16x32_bf16(afr[r][0][0], b0, acc0, 0, 0, 0);
      acc0 = __builtin_amdgcn_mfma_f32_16x16x32_bf16(afr[r][0][1], b1, acc0, 0, 0, 0);
      acc1 = __builtin_amdgcn_mfma_f32_16x16x32_bf16(afr[r][1][0], b0, acc1, 0, 0, 0);
      acc1 = __builtin_amdgcn_mfma_f32_16x16x32_bf16(afr[r][1][1], b1, acc1, 0, 0, 0);
      // exec-masked maxes: all lanes ran the (convergent) MFMAs above;
      // only member lanes fold their column into the ring's running max.
      if (rr == r) {
#pragma unroll
        for (int p = 0; p < 4; ++p) {
          rmax[0][r][p] = fmaxf(rmax[0][r][p], acc0[p]);
          rmax[1][r][p] = fmaxf(rmax[1][r][p], acc1[p]);
        }
      }
    }
  }

  // reduce over the 16 point-columns (lane bits 0-3); one atomic per
  // (ring, chan) from the l16==0 lane of each quad.
#pragma unroll
  for (int tt = 0; tt < 2; ++tt) {
#pragma unroll
    for (int r = 0; r < NR; ++r) {
#pragma unroll
      for (int p = 0; p < 4; ++p) {
        float v = rmax[tt][r][p];
        v = fmaxf(v, __shfl_xor(v, 1, 64));
        v = fmaxf(v, __shfl_xor(v, 2, 64));
        v = fmaxf(v, __shfl_xor(v, 4, 64));
        v = fmaxf(v, __shfl_xor(v, 8, 64));
        if (l16 == 0) {
          const int chan = (wave + 4 * tt) * 16 + quad * 4 + p;
          const unsigned int u = __float_as_uint(v);
          const unsigned int key = (u & 0x80000000u) ? ~u : (u | 0x80000000u);
          atomicMax(&smax_keys[(size_t)(b * NR + r) * DOUT + chan], key);
        }
      }
    }
  }
}

// ---------------------------------------------------------------------------
// K2: finalize affine on the 16K maxima, broadcast to out[b][o][n] =
// ymax[b][ring[b,n]][o].  EXACTLY r3's kernel (passed, ~71us) with ONE
// change: PLAIN float4 stores instead of __builtin_nontemporal_store.
// nt (L2-bypass) is the sole invariant shared by every ~70us k_out variant
// (r0/r1/r3/r4) while the fill kernel's plain stores hit 6.9 TB/s with the
// same 1KB-per-instr coalescing -- this round is the A/B.
__global__ void __launch_bounds__(256) k_out(
    const float* __restrict__ bias, const float* __restrict__ gamma,
    const float* __restrict__ beta, const float* __restrict__ mean,
    const float* __restrict__ var, const int* __restrict__ ring,
    const unsigned int* __restrict__ smax_keys, float* __restrict__ out) {
  const int b = blockIdx.z;
  const int og = blockIdx.y;  // 32-channel group
  const int n0 = blockIdx.x * 1024;
  const int t = (int)threadIdx.x;

  __shared__ float lut[32 * NR * 32];  // [oo][r][c32], 16 KB
  {
    // thread t computes ONE (oo, r) value and writes 16 replicas
    const int oo = t >> 3;
    const int r = (t >> 1) & 3;
    const int c0 = (t & 1) * 16;
    const int o = og * 32 + oo;
    const int tt = r * DOUT + o;
    const unsigned int key = smax_keys[(size_t)b * NR * DOUT + tt];
    const unsigned int u = (key & 0x80000000u) ? (key ^ 0x80000000u) : ~key;
    const float raw = __uint_as_float(u);
    const float sc = gamma[tt] * rsqrtf(var[tt] + BN_EPS);
    const float val = (raw + bias[tt] - mean[tt]) * sc + beta[tt];
    nfloat4 v4 = {val, val, val, val};
    float* dst = &lut[(oo * NR + r) * 32 + c0];
#pragma unroll
    for (int k = 0; k < 4; ++k) *(nfloat4*)&dst[k * 4] = v4;
  }
  __syncthreads();

  const int n = n0 + t * 4;
  const int4 rg = *(const int4*)&ring[(size_t)b * NN + n];
  const int l31 = t & 31;
  // loop-invariant per-component gather bases (float index into lut)
  const float* p0 = &lut[rg.x * 32 + l31];
  const float* p1 = &lut[rg.y * 32 + l31];
  const float* p2 = &lut[rg.z * 32 + l31];
  const float* p3 = &lut[rg.w * 32 + l31];
  float* orow = out + ((size_t)b * DOUT + og * 32) * NN + n;

#pragma unroll 8
  for (int oo = 0; oo < 32; ++oo) {
    nfloat4 v;
    v.x = p0[oo * 128];  // ds_read_b32 ... offset:oo*512, conflict-free
    v.y = p1[oo * 128];
    v.z = p2[oo * 128];
    v.w = p3[oo * 128];
    *(nfloat4*)(orow + (size_t)oo * NN) = v;  // PLAIN store (A/B vs nt)
  }
}

// ---------------------------------------------------------------------------
extern "C" void kernel_launch(void* const* d_in, const int* in_sizes, int n_in,
                              void* d_out, int out_size, void* d_ws, size_t ws_size,
                              hipStream_t stream) {
  const float* x = (const float*)d_in[0];
  const int* ring = (const int*)d_in[1];
  const float* W = (const float*)d_in[2];
  const float* bias = (const float*)d_in[3];
  const float* gamma = (const float*)d_in[4];
  const float* beta = (const float*)d_in[5];
  const float* mean = (const float*)d_in[6];
  const float* var = (const float*)d_in[7];
  float* out = (float*)d_out;

  unsigned int* keys = (unsigned int*)d_ws;

  // zero smax keys (key 0 decodes below every real key)
  (void)hipMemsetAsync(keys, 0, (size_t)BB * NR * DOUT * 4, stream);

  k_compute<<<dim3(NN / 256, BB), 256, 0, stream>>>(x, W, ring, keys);
  k_out<<<dim3(NN / 1024, DOUT / 32, BB), 256, 0, stream>>>(bias, gamma, beta, mean,
                                                            var, ring, keys, out);
}

// Round 8
// 233.503 us; speedup vs baseline: 1.0011x; 1.0011x over previous
//
#include <hip/hip_runtime.h>
#include <hip/hip_bf16.h>
#include <cstdint>
#include <cstddef>

// Problem constants (fixed by reference)
#define BB 32
#define NN 8192
#define DIN 64
#define DOUT 128
#define NR 4
#define BN_EPS 1e-5f
#define CHUNKS 32  // NN / 256

typedef float nfloat4 __attribute__((ext_vector_type(4)));
typedef float floatx4 __attribute__((ext_vector_type(4)));
typedef short short8 __attribute__((ext_vector_type(8)));

// Workspace: float part[BB*CHUNKS][NR][DOUT] = 2 MB of per-chunk partial
// maxima. NO atomics, NO memset: every slot is fully overwritten by its
// owning block (each block covers all 4 rings x 128 chans), so the
// harness's workspace poison is harmless. k1->k2 visibility is via the
// kernel-dispatch boundary (same as every passing round r0-r7).
//
// WHY: r0-r7 invariant audit. k_compute's issue-work is ~6us yet it
// measures ~75us under THREE different load structures; the untouched
// invariant was 524,288 device-scope atomicMax onto a 64KB table (512
// contended RMWs per address, memory-side). r0's counter row shows 8MB of
// WRITE_SIZE from a kernel that stores 64KB -- the atomic RMW traffic.

__device__ inline void pack2(float a, float b, short8& dst, int idx) {
  // packed f32x2 -> bf16x2 (compiler emits v_cvt_pk_bf16_f32 on gfx950)
  __hip_bfloat162 h = __float22bfloat162_rn(make_float2(a, b));
  const unsigned int bits = *(unsigned int*)&h;
  dst[idx] = (short)(bits & 0xffffu);
  dst[idx + 1] = (short)(bits >> 16);
}

// LDS 16B-group swizzle: distinct across any 8 consecutive lanes for BOTH
// the stage writes (n = 4*lane+i) and the fragment reads (n = T*16+l16).
__device__ inline int swz(int n) { return (n ^ (n >> 2) ^ (n >> 5)) & 7; }

// ---------------------------------------------------------------------------
// K1 (MFMA): block = (b, 256-point chunk), 4 waves. Wave w owns channel
// tiles {w, w+4}. Stage: wave reads its 16 d-rows as 1KB sequential float4
// bursts, in-register 8x4 transpose, bf16 pack, swizzled ds_write_b128;
// T-loop = 2 ds_read_b128 + 16 MFMA + exec-masked running max.
// Epilogue: 16-pt butterfly, then ONE PLAIN STORE per (ring,chan) into the
// block's PRIVATE partial slot -- zero atomics.
__global__ void __launch_bounds__(256) k_compute(
    const float* __restrict__ x, const float* __restrict__ W,
    const int* __restrict__ ring, float* __restrict__ part) {
  const int b = blockIdx.y;
  const int cx = blockIdx.x;
  const int n0 = cx * 256;
  const int wave = (int)threadIdx.x >> 6;
  const int lane = (int)threadIdx.x & 63;
  const int quad = lane >> 4;
  const int l16 = lane & 15;
  const float* xb = x + (size_t)b * DIN * NN;
  const int* rgb = ring + (size_t)b * NN;

  // bf16 tile, [n=256][8 groups of 8 d], 16B units, XOR-swizzled: 32 KB
  __shared__ short8 lx[256 * 8];

  // ---- stage
  {
    const float* xr = xb + (size_t)(wave * 16) * NN + n0 + 4 * lane;
#pragma unroll
    for (int grp = 0; grp < 2; ++grp) {
      nfloat4 L[8];
#pragma unroll
      for (int j = 0; j < 8; ++j)
        L[j] = *(const nfloat4*)&xr[(size_t)(grp * 8 + j) * NN];
#pragma unroll
      for (int i = 0; i < 4; ++i) {
        short8 v;
        pack2(L[0][i], L[1][i], v, 0);
        pack2(L[2][i], L[3][i], v, 2);
        pack2(L[4][i], L[5][i], v, 4);
        pack2(L[6][i], L[7][i], v, 6);
        const int ni = 4 * lane + i;  // point column within the tile
        lx[ni * 8 + ((wave * 2 + grp) ^ swz(ni))] = v;
      }
    }
  }

  // A fragments for all 4 rings: afr[r][tile][kstep], A[m=l16][k=quad*8+j].
  short8 afr[NR][2][2];
#pragma unroll
  for (int r = 0; r < NR; ++r) {
#pragma unroll
    for (int tt = 0; tt < 2; ++tt) {
      const int chan = (wave + 4 * tt) * 16 + l16;
      const float* wr = W + ((size_t)r * DOUT + chan) * DIN + quad * 8;
#pragma unroll
      for (int ks = 0; ks < 2; ++ks) {
        const float4 w0 = *(const float4*)&wr[ks * 32];
        const float4 w1 = *(const float4*)&wr[ks * 32 + 4];
        short8 a;
        pack2(w0.x, w0.y, a, 0);
        pack2(w0.z, w0.w, a, 2);
        pack2(w1.x, w1.y, a, 4);
        pack2(w1.z, w1.w, a, 6);
        afr[r][tt][ks] = a;
      }
    }
  }

  floatx4 rmax[2][NR];
#pragma unroll
  for (int tt = 0; tt < 2; ++tt)
#pragma unroll
    for (int r = 0; r < NR; ++r)
      rmax[tt][r] = {-INFINITY, -INFINITY, -INFINITY, -INFINITY};

  __syncthreads();  // staged tile visible to all waves

#pragma unroll 4
  for (int T = 0; T < 16; ++T) {
    const int n = T * 16 + l16;
    const short8 b0 = lx[n * 8 + (quad ^ swz(n))];        // d = quad*8+j
    const short8 b1 = lx[n * 8 + ((4 + quad) ^ swz(n))];  // d = 32+quad*8+j
    const int rr = rgb[n0 + n];
#pragma unroll
    for (int r = 0; r < NR; ++r) {
      floatx4 acc0 = {0.f, 0.f, 0.f, 0.f};
      floatx4 acc1 = {0.f, 0.f, 0.f, 0.f};
      acc0 = __builtin_amdgcn_mfma_f32_16x16x32_bf16(afr[r][0][0], b0, acc0, 0, 0, 0);
      acc0 = __builtin_amdgcn_mfma_f32_16x16x32_bf16(afr[r][0][1], b1, acc0, 0, 0, 0);
      acc1 = __builtin_amdgcn_mfma_f32_16x16x32_bf16(afr[r][1][0], b0, acc1, 0, 0, 0);
      acc1 = __builtin_amdgcn_mfma_f32_16x16x32_bf16(afr[r][1][1], b1, acc1, 0, 0, 0);
      if (rr == r) {  // exec-masked fold; MFMAs above stay convergent
#pragma unroll
        for (int p = 0; p < 4; ++p) {
          rmax[0][r][p] = fmaxf(rmax[0][r][p], acc0[p]);
          rmax[1][r][p] = fmaxf(rmax[1][r][p], acc1[p]);
        }
      }
    }
  }

  // reduce over the 16 point-columns; ONE PLAIN STORE per (ring, chan)
  // into this block's private partial slot (no atomics, no contention).
  float* slot = part + (size_t)(b * CHUNKS + cx) * NR * DOUT;
#pragma unroll
  for (int tt = 0; tt < 2; ++tt) {
#pragma unroll
    for (int r = 0; r < NR; ++r) {
#pragma unroll
      for (int p = 0; p < 4; ++p) {
        float v = rmax[tt][r][p];
        v = fmaxf(v, __shfl_xor(v, 1, 64));
        v = fmaxf(v, __shfl_xor(v, 2, 64));
        v = fmaxf(v, __shfl_xor(v, 4, 64));
        v = fmaxf(v, __shfl_xor(v, 8, 64));
        if (l16 == 0) {
          const int chan = (wave + 4 * tt) * 16 + quad * 4 + p;
          slot[r * DOUT + chan] = v;
        }
      }
    }
  }
}

// ---------------------------------------------------------------------------
// K2: reduce the 32 per-chunk partials, finalize affine, broadcast:
// out[b][o][n] = ymax[b][ring[b,n]][o].  Gather/store body is r7-verbatim
// (best measured variant); only the LUT stage changed: each LUT thread max-
// reduces its (o, r) over the 32 chunk slots (32 independent unrolled loads,
// L2/L3-served -- the 2MB part table is hot).
__global__ void __launch_bounds__(256) k_out(
    const float* __restrict__ bias, const float* __restrict__ gamma,
    const float* __restrict__ beta, const float* __restrict__ mean,
    const float* __restrict__ var, const int* __restrict__ ring,
    const float* __restrict__ part, float* __restrict__ out) {
  const int b = blockIdx.z;
  const int og = blockIdx.y;  // 32-channel group
  const int n0 = blockIdx.x * 1024;
  const int t = (int)threadIdx.x;

  __shared__ float lut[32 * NR * 32];  // [oo][r][c32], 16 KB
  {
    // thread t computes ONE (oo, r) value and writes 16 replicas
    const int oo = t >> 3;
    const int r = (t >> 1) & 3;
    const int c0 = (t & 1) * 16;
    const int o = og * 32 + oo;
    const float* ps = part + (size_t)b * CHUNKS * NR * DOUT + r * DOUT + o;
    float raw = -INFINITY;
#pragma unroll
    for (int c = 0; c < CHUNKS; ++c)
      raw = fmaxf(raw, ps[(size_t)c * NR * DOUT]);
    const int tt = r * DOUT + o;
    const float sc = gamma[tt] * rsqrtf(var[tt] + BN_EPS);
    const float val = (raw + bias[tt] - mean[tt]) * sc + beta[tt];
    nfloat4 v4 = {val, val, val, val};
    float* dst = &lut[(oo * NR + r) * 32 + c0];
#pragma unroll
    for (int k = 0; k < 4; ++k) *(nfloat4*)&dst[k * 4] = v4;
  }
  __syncthreads();

  const int n = n0 + t * 4;
  const int4 rg = *(const int4*)&ring[(size_t)b * NN + n];
  const int l31 = t & 31;
  // loop-invariant per-component gather bases (float index into lut)
  const float* p0 = &lut[rg.x * 32 + l31];
  const float* p1 = &lut[rg.y * 32 + l31];
  const float* p2 = &lut[rg.z * 32 + l31];
  const float* p3 = &lut[rg.w * 32 + l31];
  float* orow = out + ((size_t)b * DOUT + og * 32) * NN + n;

#pragma unroll 8
  for (int oo = 0; oo < 32; ++oo) {
    nfloat4 v;
    v.x = p0[oo * 128];  // ds_read_b32 ... offset:oo*512, conflict-free
    v.y = p1[oo * 128];
    v.z = p2[oo * 128];
    v.w = p3[oo * 128];
    *(nfloat4*)(orow + (size_t)oo * NN) = v;  // plain store
  }
}

// ---------------------------------------------------------------------------
extern "C" void kernel_launch(void* const* d_in, const int* in_sizes, int n_in,
                              void* d_out, int out_size, void* d_ws, size_t ws_size,
                              hipStream_t stream) {
  const float* x = (const float*)d_in[0];
  const int* ring = (const int*)d_in[1];
  const float* W = (const float*)d_in[2];
  const float* bias = (const float*)d_in[3];
  const float* gamma = (const float*)d_in[4];
  const float* beta = (const float*)d_in[5];
  const float* mean = (const float*)d_in[6];
  const float* var = (const float*)d_in[7];
  float* out = (float*)d_out;

  float* part = (float*)d_ws;  // 2 MB, fully overwritten -> no memset

  k_compute<<<dim3(CHUNKS, BB), 256, 0, stream>>>(x, W, ring, part);
  k_out<<<dim3(NN / 1024, DOUT / 32, BB), 256, 0, stream>>>(bias, gamma, beta, mean,
                                                            var, ring, part, out);
}